// Round 1
// baseline (126.050 us; speedup 1.0000x reference)
//
#include <hip/hip_runtime.h>
#include <math.h>

// CrowdDet RetinaNet loss constants
#define POS_T 0.5f
#define NEG_T 0.4f
#define F_ALPHA 0.25f
#define SL1_BETA 0.1f

__device__ __forceinline__ float smooth_l1(float d) {
    d = fabsf(d);
    return d < SL1_BETA ? 0.5f * d * d / SL1_BETA : d - SL1_BETA;
}

// ws layout: [0]=loss_cls sum (double), [1]=loss_reg sum, [2]=num_pos
__global__ __launch_bounds__(256) void retina_loss_kernel(
    const float* __restrict__ pred_cls,   // [B,A,1]
    const float* __restrict__ pred_reg,   // [B,A,4]
    const float* __restrict__ anchors,    // [A,4]
    const float* __restrict__ gt_boxes,   // [B,G,5]
    const float* __restrict__ im_info,    // [B,6]
    int A, int G,
    double* __restrict__ ws)
{
#pragma clang fp contract(off)
    const int b = blockIdx.y;
    const int a = blockIdx.x * 256 + threadIdx.x;
    const float* __restrict__ gtb = gt_boxes + (size_t)b * G * 5;
    const int nvalid = (int)im_info[b * 6 + 5];   // uniform scalar load

    float lc = 0.f, lr = 0.f;
    int fg = 0;

    if (a < A) {
        const float4 anc = *reinterpret_cast<const float4*>(anchors + 4 * (size_t)a);
        const float a0 = anc.x, a1 = anc.y, a2 = anc.z, a3 = anc.w;
        const float aw = a2 - a0 + 1.f;
        const float ah = a3 - a1 + 1.f;
        const float area_a = aw * ah;

        // IoU argmax over valid gts. gtb[] indexed by uniform g -> s_loads.
        // Masked gts (g >= nvalid) get ov=-1 in the reference and can never
        // win (unmasked g=0 gives ov >= 0), so we simply don't visit them.
        float max_ov = -2.0f;
        int arg = 0;
        #pragma unroll 4
        for (int g = 0; g < nvalid; ++g) {
            const float g0 = gtb[g * 5 + 0];
            const float g1 = gtb[g * 5 + 1];
            const float g2 = gtb[g * 5 + 2];
            const float g3 = gtb[g * 5 + 3];
            const float area_g = (g2 - g0 + 1.f) * (g3 - g1 + 1.f);
            const float iw = fminf(a2, g2) - fmaxf(a0, g0) + 1.f;
            const float ih = fminf(a3, g3) - fmaxf(a1, g1) + 1.f;
            const float inter = fmaxf(iw, 0.f) * fmaxf(ih, 0.f);
            const float ov = inter / (area_a + area_g - inter);
            if (ov > max_ov) { max_ov = ov; arg = g; }   // strict > == first-max
        }

        float label = 0.f;
        bool valid = true;
        if (max_ov >= POS_T) {
            label = gtb[arg * 5 + 4];          // per-lane gather, fg only
        } else if (max_ov >= NEG_T) {
            valid = false;                     // ignore band
        }
        fg = (label > 0.f) ? 1 : 0;

        if (valid) {
            const float x = pred_cls[(size_t)b * A + a];
            const float p = 1.f / (1.f + expf(-x));
            const float l1p = log1pf(expf(-fabsf(x)));
            const float log_p  = fminf(x, 0.f) - l1p;    // log_sigmoid(x)
            const float log_np = fminf(-x, 0.f) - l1p;   // log_sigmoid(-x)
            const float pos = (label == 1.f) ? 1.f : 0.f;
            const float omp = 1.f - p;
            lc = -(F_ALPHA * pos * (omp * omp) * log_p
                   + (1.f - F_ALPHA) * (1.f - pos) * (p * p) * log_np);
        }

        if (fg) {
            const float g0 = gtb[arg * 5 + 0];
            const float g1 = gtb[arg * 5 + 1];
            const float g2 = gtb[arg * 5 + 2];
            const float g3 = gtb[arg * 5 + 3];
            const float gw = g2 - g0 + 1.f;
            const float gh = g3 - g1 + 1.f;
            const float gx = g0 + 0.5f * gw;
            const float gy = g1 + 0.5f * gh;
            const float axc = a0 + 0.5f * aw;
            const float ayc = a1 + 0.5f * ah;
            const float t0 = (gx - axc) / aw;
            const float t1 = (gy - ayc) / ah;
            const float t2 = logf(gw / aw);
            const float t3 = logf(gh / ah);
            const float4 r = *reinterpret_cast<const float4*>(
                pred_reg + 4 * ((size_t)b * A + a));
            lr = smooth_l1(r.x - t0) + smooth_l1(r.y - t1)
               + smooth_l1(r.z - t2) + smooth_l1(r.w - t3);
        }
    }

    // wave64 reduction
    const unsigned long long bal = __ballot(fg != 0);
    int wnp = __popcll(bal);
    for (int off = 32; off > 0; off >>= 1) {
        lc += __shfl_down(lc, off);
        lr += __shfl_down(lr, off);
    }

    __shared__ float s_lc[4], s_lr[4];
    __shared__ int s_np[4];
    const int wid = threadIdx.x >> 6;
    const int lane = threadIdx.x & 63;
    if (lane == 0) { s_lc[wid] = lc; s_lr[wid] = lr; s_np[wid] = wnp; }
    __syncthreads();
    if (threadIdx.x == 0) {
        const float tlc = s_lc[0] + s_lc[1] + s_lc[2] + s_lc[3];
        const float tlr = s_lr[0] + s_lr[1] + s_lr[2] + s_lr[3];
        const int   tnp = s_np[0] + s_np[1] + s_np[2] + s_np[3];
        __hip_atomic_fetch_add(&ws[0], (double)tlc, __ATOMIC_RELAXED, __HIP_MEMORY_SCOPE_AGENT);
        __hip_atomic_fetch_add(&ws[1], (double)tlr, __ATOMIC_RELAXED, __HIP_MEMORY_SCOPE_AGENT);
        __hip_atomic_fetch_add(&ws[2], (double)tnp, __ATOMIC_RELAXED, __HIP_MEMORY_SCOPE_AGENT);
    }
}

__global__ void finalize_kernel(const double* __restrict__ ws, float* __restrict__ out) {
    if (threadIdx.x == 0 && blockIdx.x == 0) {
        const double npos = ws[2] < 1.0 ? 1.0 : ws[2];
        const double norm = 0.9 * 100.0 + 0.1 * npos;
        out[0] = (float)(ws[0] / norm);
        out[1] = (float)(ws[1] / norm);
    }
}

extern "C" void kernel_launch(void* const* d_in, const int* in_sizes, int n_in,
                              void* d_out, int out_size, void* d_ws, size_t ws_size,
                              hipStream_t stream) {
    const float* pred_cls = (const float*)d_in[0];
    const float* pred_reg = (const float*)d_in[1];
    const float* anchors  = (const float*)d_in[2];
    const float* gt_boxes = (const float*)d_in[3];
    const float* im_info  = (const float*)d_in[4];

    const int A = in_sizes[2] / 4;
    const int B = in_sizes[4] / 6;
    const int G = in_sizes[3] / (B * 5);

    double* ws = (double*)d_ws;
    hipMemsetAsync(ws, 0, 3 * sizeof(double), stream);

    dim3 grid((A + 255) / 256, B);
    retina_loss_kernel<<<grid, 256, 0, stream>>>(
        pred_cls, pred_reg, anchors, gt_boxes, im_info, A, G, ws);
    finalize_kernel<<<1, 1, 0, stream>>>(ws, (float*)d_out);
}

// Round 2
// 107.614 us; speedup vs baseline: 1.1713x; 1.1713x over previous
//
#include <hip/hip_runtime.h>
#include <math.h>

// CrowdDet RetinaNet loss constants
#define POS_T 0.5f
#define NEG_T 0.4f
#define F_ALPHA 0.25f
#define SL1_BETA 0.1f

// d_ws layout:
//   bytes [0,24)    : 3 doubles  (loss_cls, loss_reg, num_pos accumulators)
//   bytes [512, ...) : prepped GT data, stride 8 floats per gt:
//                      {g0, g1, g2, g3, area_g, cls, pad, pad}
#define WS_GT_BYTE_OFF 512

__device__ __forceinline__ float smooth_l1(float d) {
    d = fabsf(d);
    return d < SL1_BETA ? 0.5f * d * d / SL1_BETA : d - SL1_BETA;
}

__global__ void prep_gt_kernel(const float* __restrict__ gt, float* __restrict__ gtp,
                               int total) {
#pragma clang fp contract(off)
    const int i = blockIdx.x * 256 + threadIdx.x;
    if (i < total) {
        const float* s = gt + (size_t)i * 5;
        const float g0 = s[0], g1 = s[1], g2 = s[2], g3 = s[3], cls = s[4];
        // area with exact reference op order: ((g2-g0)+1) * ((g3-g1)+1)
        const float area_g = (g2 - g0 + 1.f) * (g3 - g1 + 1.f);
        float4* d = reinterpret_cast<float4*>(gtp + (size_t)i * 8);
        d[0] = make_float4(g0, g1, g2, g3);
        d[1] = make_float4(area_g, cls, 0.f, 0.f);
    }
}

__global__ __launch_bounds__(256) void retina_loss_kernel(
    const float* __restrict__ pred_cls,   // [B,A,1]
    const float* __restrict__ pred_reg,   // [B,A,4]
    const float* __restrict__ anchors,    // [A,4]
    const float* __restrict__ gt_boxes,   // [B,G,5]  (original, for rare tails)
    const float* __restrict__ im_info,    // [B,6]
    const float* __restrict__ gtp_all,    // [B,G,8]  prepped
    int A, int G,
    double* __restrict__ ws)
{
#pragma clang fp contract(off)
    const int b = blockIdx.y;
    const int a_raw = blockIdx.x * 256 + threadIdx.x;
    const bool live = a_raw < A;
    const int a = live ? a_raw : (A - 1);          // clamp: keep control flow uniform
    const float* __restrict__ gtb = gt_boxes + (size_t)b * G * 5;
    const float* __restrict__ gtp = gtp_all + (size_t)b * G * 8;
    const int nvalid = (int)im_info[b * 6 + 5];    // uniform

    const float4 anc = *reinterpret_cast<const float4*>(anchors + 4 * (size_t)a);
    const float a0 = anc.x, a1 = anc.y, a2 = anc.z, a3 = anc.w;
    const float aw = a2 - a0 + 1.f;
    const float ah = a3 - a1 + 1.f;
    const float area_a = aw * ah;

    // IoU argmax via cross-multiplied comparison (division-free inner loop).
    // iou = inter/(S - inter) is monotone in inter/S, so for positives
    // iou_i > iou_j  <=>  inter_i * S_j > inter_j * S_i.
    // Init (-1, 1) guarantees the first gt always wins (inter >= 0 > -S).
    float best_inter = -1.f, best_S = 1.f;
    int arg = 0;
    #pragma unroll 4
    for (int g = 0; g < nvalid; ++g) {
        const float* gp = gtp + (size_t)g * 8;     // uniform address -> s_load
        const float g0 = gp[0];
        const float g1 = gp[1];
        const float g2 = gp[2];
        const float g3 = gp[3];
        const float sg = gp[4];
        const float iw = fminf(a2, g2) - fmaxf(a0, g0) + 1.f;  // exact ref order
        const float ih = fminf(a3, g3) - fmaxf(a1, g1) + 1.f;
        const float inter = fmaxf(iw, 0.f) * fmaxf(ih, 0.f);
        const float S = area_a + sg;
        const bool upd = inter * best_S > best_inter * S;      // strict > = first-max
        best_inter = upd ? inter : best_inter;
        best_S     = upd ? S     : best_S;
        arg        = upd ? g     : arg;
    }
    // ONE division, with the exact reference expression/rounding:
    // ov = inter / ((area_a + area_g) - inter)
    const float max_ov = best_inter / (best_S - best_inter);

    float lc = 0.f, lr = 0.f;
    int fg = 0;

    if (live) {
        float label = 0.f;
        bool valid = true;
        if (max_ov >= POS_T) {
            label = gtb[(size_t)arg * 5 + 4];      // per-lane gather, fg only
        } else if (max_ov >= NEG_T) {
            valid = false;                         // ignore band
        }
        fg = (label > 0.f) ? 1 : 0;

        if (valid) {
            const float x = pred_cls[(size_t)b * A + a];
            const float p = 1.f / (1.f + expf(-x));
            const float l1p = log1pf(expf(-fabsf(x)));
            const float log_p  = fminf(x, 0.f) - l1p;    // log_sigmoid(x)
            const float log_np = fminf(-x, 0.f) - l1p;   // log_sigmoid(-x)
            const float pos = (label == 1.f) ? 1.f : 0.f;
            const float omp = 1.f - p;
            lc = -(F_ALPHA * pos * (omp * omp) * log_p
                   + (1.f - F_ALPHA) * (1.f - pos) * (p * p) * log_np);
        }

        if (fg) {
            const float g0 = gtb[(size_t)arg * 5 + 0];
            const float g1 = gtb[(size_t)arg * 5 + 1];
            const float g2 = gtb[(size_t)arg * 5 + 2];
            const float g3 = gtb[(size_t)arg * 5 + 3];
            const float gw = g2 - g0 + 1.f;
            const float gh = g3 - g1 + 1.f;
            const float gx = g0 + 0.5f * gw;
            const float gy = g1 + 0.5f * gh;
            const float axc = a0 + 0.5f * aw;
            const float ayc = a1 + 0.5f * ah;
            const float t0 = (gx - axc) / aw;
            const float t1 = (gy - ayc) / ah;
            const float t2 = logf(gw / aw);
            const float t3 = logf(gh / ah);
            const float4 r = *reinterpret_cast<const float4*>(
                pred_reg + 4 * ((size_t)b * A + a));
            lr = smooth_l1(r.x - t0) + smooth_l1(r.y - t1)
               + smooth_l1(r.z - t2) + smooth_l1(r.w - t3);
        }
    }

    // wave64 reduction
    const unsigned long long bal = __ballot(fg != 0);
    int wnp = __popcll(bal);
    for (int off = 32; off > 0; off >>= 1) {
        lc += __shfl_down(lc, off);
        lr += __shfl_down(lr, off);
    }

    __shared__ float s_lc[4], s_lr[4];
    __shared__ int s_np[4];
    const int wid = threadIdx.x >> 6;
    const int lane = threadIdx.x & 63;
    if (lane == 0) { s_lc[wid] = lc; s_lr[wid] = lr; s_np[wid] = wnp; }
    __syncthreads();
    if (threadIdx.x == 0) {
        const float tlc = s_lc[0] + s_lc[1] + s_lc[2] + s_lc[3];
        const float tlr = s_lr[0] + s_lr[1] + s_lr[2] + s_lr[3];
        const int   tnp = s_np[0] + s_np[1] + s_np[2] + s_np[3];
        __hip_atomic_fetch_add(&ws[0], (double)tlc, __ATOMIC_RELAXED, __HIP_MEMORY_SCOPE_AGENT);
        __hip_atomic_fetch_add(&ws[1], (double)tlr, __ATOMIC_RELAXED, __HIP_MEMORY_SCOPE_AGENT);
        __hip_atomic_fetch_add(&ws[2], (double)tnp, __ATOMIC_RELAXED, __HIP_MEMORY_SCOPE_AGENT);
    }
}

__global__ void finalize_kernel(const double* __restrict__ ws, float* __restrict__ out) {
    if (threadIdx.x == 0 && blockIdx.x == 0) {
        const double npos = ws[2] < 1.0 ? 1.0 : ws[2];
        const double norm = 0.9 * 100.0 + 0.1 * npos;
        out[0] = (float)(ws[0] / norm);
        out[1] = (float)(ws[1] / norm);
    }
}

extern "C" void kernel_launch(void* const* d_in, const int* in_sizes, int n_in,
                              void* d_out, int out_size, void* d_ws, size_t ws_size,
                              hipStream_t stream) {
    const float* pred_cls = (const float*)d_in[0];
    const float* pred_reg = (const float*)d_in[1];
    const float* anchors  = (const float*)d_in[2];
    const float* gt_boxes = (const float*)d_in[3];
    const float* im_info  = (const float*)d_in[4];

    const int A = in_sizes[2] / 4;
    const int B = in_sizes[4] / 6;
    const int G = in_sizes[3] / (B * 5);

    double* ws = (double*)d_ws;
    float*  gtp = (float*)((char*)d_ws + WS_GT_BYTE_OFF);

    hipMemsetAsync(ws, 0, 3 * sizeof(double), stream);

    const int total_gt = B * G;
    prep_gt_kernel<<<(total_gt + 255) / 256, 256, 0, stream>>>(gt_boxes, gtp, total_gt);

    dim3 grid((A + 255) / 256, B);
    retina_loss_kernel<<<grid, 256, 0, stream>>>(
        pred_cls, pred_reg, anchors, gt_boxes, im_info, gtp, A, G, ws);
    finalize_kernel<<<1, 1, 0, stream>>>(ws, (float*)d_out);
}

// Round 3
// 89.481 us; speedup vs baseline: 1.4087x; 1.2026x over previous
//
#include <hip/hip_runtime.h>
#include <math.h>

// CrowdDet RetinaNet loss constants
#define POS_T 0.5f
#define NEG_T 0.4f
#define F_ALPHA 0.25f
#define SL1_BETA 0.1f

// d_ws layout:
//   bytes [0,24)     : 3 doubles (loss_cls, loss_reg, num_pos accumulators)
//   bytes [512, ...) : prepped GT data, stride 8 floats per gt:
//                      {g0, g1, g2, g3, area_g, cls, pad, pad}
#define WS_GT_BYTE_OFF 512

__device__ __forceinline__ float smooth_l1(float d) {
    d = fabsf(d);
    return d < SL1_BETA ? 0.5f * d * d / SL1_BETA : d - SL1_BETA;
}

__global__ void prep_gt_kernel(const float* __restrict__ gt, float* __restrict__ gtp,
                               int total) {
#pragma clang fp contract(off)
    const int i = blockIdx.x * 256 + threadIdx.x;
    if (i < total) {
        const float* s = gt + (size_t)i * 5;
        const float g0 = s[0], g1 = s[1], g2 = s[2], g3 = s[3], cls = s[4];
        const float area_g = (g2 - g0 + 1.f) * (g3 - g1 + 1.f);  // exact ref order
        float4* d = reinterpret_cast<float4*>(gtp + (size_t)i * 8);
        d[0] = make_float4(g0, g1, g2, g3);
        d[1] = make_float4(area_g, cls, 0.f, 0.f);
    }
}

// Per-anchor epilogue: focal + smooth-L1 contributions.
__device__ __forceinline__ void epilogue(
    bool live, float a0, float a1, float a2, float a3, float aw, float ah,
    float best_inter, float best_S, int arg,
    const float* __restrict__ gtp,
    const float* __restrict__ pred_cls_elem,   // &pred_cls[b*A + a]
    const float* __restrict__ pred_reg_elem,   // &pred_reg[(b*A + a)*4]
    float& lc, float& lr, int& fg)
{
#pragma clang fp contract(off)
    if (!live) return;
    // ONE division, exact reference expression: inter / ((area_a+area_g) - inter)
    const float max_ov = best_inter / (best_S - best_inter);

    float label = 0.f;
    bool valid = true;
    if (max_ov >= POS_T) {
        label = gtp[(size_t)arg * 8 + 5];
    } else if (max_ov >= NEG_T) {
        valid = false;                       // ignore band
    }
    const int f = (label > 0.f) ? 1 : 0;
    fg += f;

    if (valid) {
        const float x = *pred_cls_elem;
        const float p = 1.f / (1.f + expf(-x));
        const float l1p = log1pf(expf(-fabsf(x)));
        const float log_p  = fminf(x, 0.f) - l1p;    // log_sigmoid(x)
        const float log_np = fminf(-x, 0.f) - l1p;   // log_sigmoid(-x)
        const float pos = (label == 1.f) ? 1.f : 0.f;
        const float omp = 1.f - p;
        lc += -(F_ALPHA * pos * (omp * omp) * log_p
                + (1.f - F_ALPHA) * (1.f - pos) * (p * p) * log_np);
    }

    if (f) {
        const float4 gb = *reinterpret_cast<const float4*>(gtp + (size_t)arg * 8);
        const float gw = gb.z - gb.x + 1.f;
        const float gh = gb.w - gb.y + 1.f;
        const float gx = gb.x + 0.5f * gw;
        const float gy = gb.y + 0.5f * gh;
        const float axc = a0 + 0.5f * aw;
        const float ayc = a1 + 0.5f * ah;
        const float t0 = (gx - axc) / aw;
        const float t1 = (gy - ayc) / ah;
        const float t2 = logf(gw / aw);
        const float t3 = logf(gh / ah);
        const float4 r = *reinterpret_cast<const float4*>(pred_reg_elem);
        lr += smooth_l1(r.x - t0) + smooth_l1(r.y - t1)
            + smooth_l1(r.z - t2) + smooth_l1(r.w - t3);
    }
}

// 2 anchors per thread; uniform (SGPR) G-loop so GT reads become s_loads.
__global__ __launch_bounds__(256) void retina_loss_kernel(
    const float* __restrict__ pred_cls,   // [B,A,1]
    const float* __restrict__ pred_reg,   // [B,A,4]
    const float* __restrict__ anchors,    // [A,4]
    const float* __restrict__ im_info,    // [B,6]
    const float* __restrict__ gtp_all,    // [B,G,8] prepped
    int A, int G,
    double* __restrict__ ws)
{
#pragma clang fp contract(off)
    const int b = blockIdx.y;
    const int t = blockIdx.x * 256 + threadIdx.x;
    const int base_raw = 2 * t;
    const bool live0 = base_raw < A;
    const bool live1 = base_raw + 1 < A;
    const int base = min(base_raw, A - 2);       // clamped: loads always in-bounds

    const float* __restrict__ gtp = gtp_all + (size_t)b * G * 8;
    // Force SGPR trip count -> uniform loop -> scalar loads of GT data.
    const int nvalid = __builtin_amdgcn_readfirstlane((int)im_info[b * 6 + 5]);

    const float4 ancA = *reinterpret_cast<const float4*>(anchors + 4 * (size_t)base);
    const float4 ancB = *reinterpret_cast<const float4*>(anchors + 4 * ((size_t)base + 1));
    const float awA = ancA.z - ancA.x + 1.f, ahA = ancA.w - ancA.y + 1.f;
    const float awB = ancB.z - ancB.x + 1.f, ahB = ancB.w - ancB.y + 1.f;
    const float areaA = awA * ahA;
    const float areaB = awB * ahB;

    // Division-free IoU argmax: iou = inter/(S-inter) is monotone in inter/S,
    // so iou_i > iou_j  <=>  inter_i*S_j > inter_j*S_i (S>0). Init (-1,1)
    // makes the first gt always win. Strict > == first-max (jnp.argmax).
    float biA = -1.f, bSA = 1.f; int argA = 0;
    float biB = -1.f, bSB = 1.f; int argB = 0;

    #pragma unroll 4
    for (int g = 0; g < nvalid; ++g) {
        const float* gp = gtp + (size_t)g * 8;           // uniform -> s_load
        const float4 gb = *reinterpret_cast<const float4*>(gp);
        const float sg = gp[4];

        {
            const float iw = fminf(ancA.z, gb.z) - fmaxf(ancA.x, gb.x) + 1.f;
            const float ih = fminf(ancA.w, gb.w) - fmaxf(ancA.y, gb.y) + 1.f;
            const float inter = fmaxf(iw, 0.f) * fmaxf(ih, 0.f);
            const float S = areaA + sg;
            const bool upd = inter * bSA > biA * S;
            biA  = upd ? inter : biA;
            bSA  = upd ? S     : bSA;
            argA = upd ? g     : argA;
        }
        {
            const float iw = fminf(ancB.z, gb.z) - fmaxf(ancB.x, gb.x) + 1.f;
            const float ih = fminf(ancB.w, gb.w) - fmaxf(ancB.y, gb.y) + 1.f;
            const float inter = fmaxf(iw, 0.f) * fmaxf(ih, 0.f);
            const float S = areaB + sg;
            const bool upd = inter * bSB > biB * S;
            biB  = upd ? inter : biB;
            bSB  = upd ? S     : bSB;
            argB = upd ? g     : argB;
        }
    }

    float lc = 0.f, lr = 0.f;
    int fg = 0;
    const size_t baseA = (size_t)b * A + base;
    epilogue(live0, ancA.x, ancA.y, ancA.z, ancA.w, awA, ahA, biA, bSA, argA,
             gtp, pred_cls + baseA, pred_reg + 4 * baseA, lc, lr, fg);
    epilogue(live1, ancB.x, ancB.y, ancB.z, ancB.w, awB, ahB, biB, bSB, argB,
             gtp, pred_cls + baseA + 1, pred_reg + 4 * (baseA + 1), lc, lr, fg);

    // wave64 reduction
    for (int off = 32; off > 0; off >>= 1) {
        lc += __shfl_down(lc, off);
        lr += __shfl_down(lr, off);
        fg += __shfl_down(fg, off);
    }

    __shared__ float s_lc[4], s_lr[4];
    __shared__ int s_np[4];
    const int wid = threadIdx.x >> 6;
    const int lane = threadIdx.x & 63;
    if (lane == 0) { s_lc[wid] = lc; s_lr[wid] = lr; s_np[wid] = fg; }
    __syncthreads();
    if (threadIdx.x == 0) {
        const float tlc = s_lc[0] + s_lc[1] + s_lc[2] + s_lc[3];
        const float tlr = s_lr[0] + s_lr[1] + s_lr[2] + s_lr[3];
        const int   tnp = s_np[0] + s_np[1] + s_np[2] + s_np[3];
        __hip_atomic_fetch_add(&ws[0], (double)tlc, __ATOMIC_RELAXED, __HIP_MEMORY_SCOPE_AGENT);
        __hip_atomic_fetch_add(&ws[1], (double)tlr, __ATOMIC_RELAXED, __HIP_MEMORY_SCOPE_AGENT);
        __hip_atomic_fetch_add(&ws[2], (double)tnp, __ATOMIC_RELAXED, __HIP_MEMORY_SCOPE_AGENT);
    }
}

__global__ void finalize_kernel(const double* __restrict__ ws, float* __restrict__ out) {
    if (threadIdx.x == 0 && blockIdx.x == 0) {
        const double npos = ws[2] < 1.0 ? 1.0 : ws[2];
        const double norm = 0.9 * 100.0 + 0.1 * npos;
        out[0] = (float)(ws[0] / norm);
        out[1] = (float)(ws[1] / norm);
    }
}

extern "C" void kernel_launch(void* const* d_in, const int* in_sizes, int n_in,
                              void* d_out, int out_size, void* d_ws, size_t ws_size,
                              hipStream_t stream) {
    const float* pred_cls = (const float*)d_in[0];
    const float* pred_reg = (const float*)d_in[1];
    const float* anchors  = (const float*)d_in[2];
    const float* gt_boxes = (const float*)d_in[3];
    const float* im_info  = (const float*)d_in[4];

    const int A = in_sizes[2] / 4;
    const int B = in_sizes[4] / 6;
    const int G = in_sizes[3] / (B * 5);

    double* ws = (double*)d_ws;
    float*  gtp = (float*)((char*)d_ws + WS_GT_BYTE_OFF);

    hipMemsetAsync(ws, 0, 3 * sizeof(double), stream);

    const int total_gt = B * G;
    prep_gt_kernel<<<(total_gt + 255) / 256, 256, 0, stream>>>(gt_boxes, gtp, total_gt);

    const int threads_per_b = (A + 1) / 2;
    dim3 grid((threads_per_b + 255) / 256, B);
    retina_loss_kernel<<<grid, 256, 0, stream>>>(
        pred_cls, pred_reg, anchors, im_info, gtp, A, G, ws);
    finalize_kernel<<<1, 1, 0, stream>>>(ws, (float*)d_out);
}